// Round 1
// baseline (158.155 us; speedup 1.0000x reference)
//
#include <hip/hip_runtime.h>

#define KHH 5
#define KWW 5
#define NN 4
#define CC 20
#define HH 64
#define WW 2048

__global__ __launch_bounds__(256) void lc_xyz_kernel(
    const float* __restrict__ xyz,
    const float* __restrict__ softmax,
    const int* __restrict__ mask,
    float* __restrict__ out)
{
    const int w = blockIdx.x * blockDim.x + threadIdx.x;
    const int h = blockIdx.y;
    const int n = blockIdx.z;

    const int hw = HH * WW;
    const float* xb  = xyz + (size_t)n * 3 * hw;
    const float* smb = softmax + (size_t)n * CC * hw;
    const int*   mb  = mask + (size_t)n * hw;

    const int ctr = h * WW + w;
    const float cx = xb[0 * hw + ctr];
    const float cy = xb[1 * hw + ctr];
    const float cz = xb[2 * hw + ctr];

    float acc[CC];
#pragma unroll
    for (int c = 0; c < CC; ++c) acc[c] = 0.f;

#pragma unroll
    for (int dy = -2; dy <= 2; ++dy) {
        const int hh2 = h + dy;
        if (hh2 < 0 || hh2 >= HH) continue;   // wave-uniform (h = blockIdx.y)
#pragma unroll
        for (int dx = -2; dx <= 2; ++dx) {
            const int ww2 = w + dx;
            if (ww2 < 0 || ww2 >= WW) continue;
            const int off = hh2 * WW + ww2;
            if (mb[off] == 0) continue;       // exec-masked: no loads for masked taps
            const float ax = xb[0 * hw + off] - cx;
            const float ay = xb[1 * hw + off] - cy;
            const float az = xb[2 * hw + off] - cz;
            const float d2 = ax * ax + ay * ay + az * az;
            const float g  = __expf(-0.5f * d2);
            const float* sp = smb + off;
#pragma unroll
            for (int c = 0; c < CC; ++c)
                acc[c] = fmaf(g, sp[(size_t)c * hw], acc[c]);
        }
    }

    float* ob = out + (size_t)n * CC * hw + ctr;
#pragma unroll
    for (int c = 0; c < CC; ++c)
        ob[(size_t)c * hw] = acc[c];
}

extern "C" void kernel_launch(void* const* d_in, const int* in_sizes, int n_in,
                              void* d_out, int out_size, void* d_ws, size_t ws_size,
                              hipStream_t stream) {
    const float* xyz     = (const float*)d_in[0];
    const float* softmax = (const float*)d_in[1];
    const int*   mask    = (const int*)d_in[2];
    float*       out     = (float*)d_out;

    dim3 block(256, 1, 1);
    dim3 grid(WW / 256, HH, NN);   // 8 x 64 x 4 = 2048 blocks
    hipLaunchKernelGGL(lc_xyz_kernel, grid, block, 0, stream,
                       xyz, softmax, mask, out);
}

// Round 2
// 135.030 us; speedup vs baseline: 1.1713x; 1.1713x over previous
//
#include <hip/hip_runtime.h>

#define NN 4
#define CC 20
#define HH 64
#define WW 2048

// 2 pixels per thread, branchless mask, float2 window loads.
__global__ __launch_bounds__(256) void lc_xyz_kernel(
    const float* __restrict__ xyz,
    const float* __restrict__ softmax,
    const int* __restrict__ mask,
    float* __restrict__ out)
{
    const int t = blockIdx.x * blockDim.x + threadIdx.x;  // 0..1023: pixel pair index in row
    const int h = blockIdx.y;
    const int n = blockIdx.z;
    const int hw = HH * WW;
    const int p0 = t * 2;                                  // first of the 2 pixels

    const float* xb  = xyz     + (size_t)n * 3  * hw;
    const float* smb = softmax + (size_t)n * CC * hw;
    const int*   mb  = mask    + (size_t)n * hw;

    const int ctr = h * WW + p0;
    const float2 cxv = *(const float2*)(xb + 0 * hw + ctr);
    const float2 cyv = *(const float2*)(xb + 1 * hw + ctr);
    const float2 czv = *(const float2*)(xb + 2 * hw + ctr);

    float acc[CC][2];
#pragma unroll
    for (int c = 0; c < CC; ++c) { acc[c][0] = 0.f; acc[c][1] = 0.f; }

    // Tap window in w: [p0-2, p0+3], 6 floats, as 3 aligned float2 chunks.
    const int wbase = p0 - 2;
    int ch0 = wbase;     if (ch0 < 0) ch0 = 0;             // clamped only at t==0 (taps j=0,1 invalid there)
    const int ch1 = wbase + 2;                             // always in bounds
    int ch2 = wbase + 4; if (ch2 > WW - 2) ch2 = WW - 2;   // clamped only at t==1023 (taps j=4,5 invalid there)

    // Per-tap w-validity (only edge threads have invalid taps).
    float vf[6];
#pragma unroll
    for (int j = 0; j < 6; ++j)
        vf[j] = ((unsigned)(wbase + j) < (unsigned)WW) ? 1.f : 0.f;

#pragma unroll
    for (int dy = -2; dy <= 2; ++dy) {
        const int row = h + dy;
        if ((unsigned)row >= (unsigned)HH) continue;       // wave-uniform branch
        const int rb = row * WW;

        // Batched row loads: mask (3) + xyz (9), all independent.
        const int2 m0 = *(const int2*)(mb + rb + ch0);
        const int2 m1 = *(const int2*)(mb + rb + ch1);
        const int2 m2 = *(const int2*)(mb + rb + ch2);
        const float2 x0 = *(const float2*)(xb + 0 * hw + rb + ch0);
        const float2 x1 = *(const float2*)(xb + 0 * hw + rb + ch1);
        const float2 x2 = *(const float2*)(xb + 0 * hw + rb + ch2);
        const float2 y0 = *(const float2*)(xb + 1 * hw + rb + ch0);
        const float2 y1 = *(const float2*)(xb + 1 * hw + rb + ch1);
        const float2 y2 = *(const float2*)(xb + 1 * hw + rb + ch2);
        const float2 z0 = *(const float2*)(xb + 2 * hw + rb + ch0);
        const float2 z1 = *(const float2*)(xb + 2 * hw + rb + ch1);
        const float2 z2 = *(const float2*)(xb + 2 * hw + rb + ch2);

        const float xw[6] = {x0.x, x0.y, x1.x, x1.y, x2.x, x2.y};
        const float yw[6] = {y0.x, y0.y, y1.x, y1.y, y2.x, y2.y};
        const float zw[6] = {z0.x, z0.y, z1.x, z1.y, z2.x, z2.y};
        const float mf[6] = {vf[0] * (float)m0.x, vf[1] * (float)m0.y,
                             vf[2] * (float)m1.x, vf[3] * (float)m1.y,
                             vf[4] * (float)m2.x, vf[5] * (float)m2.y};

        // Gaussian weights: px0 uses taps j=dx, px1 uses taps j=dx+1.
        float g0[5], g1[5];
#pragma unroll
        for (int dx = 0; dx < 5; ++dx) {
            {
                const float ax = xw[dx] - cxv.x;
                const float ay = yw[dx] - cyv.x;
                const float az = zw[dx] - czv.x;
                const float d2 = ax * ax + ay * ay + az * az;
                g0[dx] = mf[dx] * __expf(-0.5f * d2);
            }
            {
                const float ax = xw[dx + 1] - cxv.y;
                const float ay = yw[dx + 1] - cyv.y;
                const float az = zw[dx + 1] - czv.y;
                const float d2 = ax * ax + ay * ay + az * az;
                g1[dx] = mf[dx + 1] * __expf(-0.5f * d2);
            }
        }

        // Channel loop: 3 float2 loads + 10 FMA per channel.
#pragma unroll
        for (int c = 0; c < CC; ++c) {
            const float* sp = smb + (size_t)c * hw + rb;
            const float2 s0 = *(const float2*)(sp + ch0);
            const float2 s1 = *(const float2*)(sp + ch1);
            const float2 s2 = *(const float2*)(sp + ch2);
            const float sw[6] = {s0.x, s0.y, s1.x, s1.y, s2.x, s2.y};
            float a0 = acc[c][0], a1 = acc[c][1];
#pragma unroll
            for (int dx = 0; dx < 5; ++dx) {
                a0 = fmaf(g0[dx], sw[dx],     a0);
                a1 = fmaf(g1[dx], sw[dx + 1], a1);
            }
            acc[c][0] = a0; acc[c][1] = a1;
        }
    }

    float* ob = out + (size_t)n * CC * hw + ctr;
#pragma unroll
    for (int c = 0; c < CC; ++c)
        *(float2*)(ob + (size_t)c * hw) = make_float2(acc[c][0], acc[c][1]);
}

extern "C" void kernel_launch(void* const* d_in, const int* in_sizes, int n_in,
                              void* d_out, int out_size, void* d_ws, size_t ws_size,
                              hipStream_t stream) {
    const float* xyz     = (const float*)d_in[0];
    const float* softmax = (const float*)d_in[1];
    const int*   mask    = (const int*)d_in[2];
    float*       out     = (float*)d_out;

    dim3 block(256, 1, 1);
    dim3 grid((WW / 2) / 256, HH, NN);   // 4 x 64 x 4 = 1024 blocks
    hipLaunchKernelGGL(lc_xyz_kernel, grid, block, 0, stream,
                       xyz, softmax, mask, out);
}

// Round 3
// 132.497 us; speedup vs baseline: 1.1936x; 1.0191x over previous
//
#include <hip/hip_runtime.h>

#define NN 4
#define CC 20
#define HH 64
#define WW 2048
#define CG 4           // channel groups
#define CPG (CC / CG)  // 5 channels per group
#define PX 4           // pixels per thread

// 4 px/thread, 5 channels/block (channel-split grid), branchless mask,
// float4 window loads with clamped aligned chunks.
__global__ __launch_bounds__(256, 4) void lc_xyz_kernel(
    const float* __restrict__ xyz,
    const float* __restrict__ softmax,
    const int* __restrict__ mask,
    float* __restrict__ out)
{
    const int t  = blockIdx.x * blockDim.x + threadIdx.x;  // pixel-quad index in row
    const int h  = blockIdx.y;
    const int nz = blockIdx.z;
    const int n  = nz >> 2;
    const int cg = nz & 3;
    const int hw = HH * WW;
    const int p0 = t * PX;

    const float* xb  = xyz     + (size_t)n * 3  * hw;
    const float* smb = softmax + (size_t)n * CC * hw + (size_t)(cg * CPG) * hw;
    const int*   mb  = mask    + (size_t)n * hw;

    const int ctr = h * WW + p0;
    const float4 cxv = *(const float4*)(xb + 0 * hw + ctr);
    const float4 cyv = *(const float4*)(xb + 1 * hw + ctr);
    const float4 czv = *(const float4*)(xb + 2 * hw + ctr);
    const float cx[PX] = {cxv.x, cxv.y, cxv.z, cxv.w};
    const float cy[PX] = {cyv.x, cyv.y, cyv.z, cyv.w};
    const float cz[PX] = {czv.x, czv.y, czv.z, czv.w};

    float acc[CPG][PX];
#pragma unroll
    for (int c = 0; c < CPG; ++c)
#pragma unroll
        for (int i = 0; i < PX; ++i) acc[c][i] = 0.f;

    // Window indices j=0..11 map to w = p0-4+j; taps use j = i+dx+2 in [2,9].
    // Aligned 16B chunks at p0-4, p0, p0+4; edge chunks clamped (their taps
    // are zeroed via validity, and all VALID taps come from unclamped chunks).
    int c0 = p0 - 4; if (c0 < 0) c0 = 0;
    const int c1 = p0;
    int c2 = p0 + 4; if (c2 > WW - 4) c2 = WW - 4;

    float vf[12];
#pragma unroll
    for (int j = 2; j <= 9; ++j)
        vf[j] = ((unsigned)(p0 - 4 + j) < (unsigned)WW) ? 1.f : 0.f;

#pragma unroll
    for (int dy = -2; dy <= 2; ++dy) {
        const int row = h + dy;
        if ((unsigned)row >= (unsigned)HH) continue;   // wave-uniform
        const int rb = row * WW;

        // Batched independent row loads: 3 int4 + 9 float4.
        const int4 m0 = *(const int4*)(mb + rb + c0);
        const int4 m1 = *(const int4*)(mb + rb + c1);
        const int4 m2 = *(const int4*)(mb + rb + c2);
        const float4 x0 = *(const float4*)(xb + 0 * hw + rb + c0);
        const float4 x1 = *(const float4*)(xb + 0 * hw + rb + c1);
        const float4 x2 = *(const float4*)(xb + 0 * hw + rb + c2);
        const float4 y0 = *(const float4*)(xb + 1 * hw + rb + c0);
        const float4 y1 = *(const float4*)(xb + 1 * hw + rb + c1);
        const float4 y2 = *(const float4*)(xb + 1 * hw + rb + c2);
        const float4 z0 = *(const float4*)(xb + 2 * hw + rb + c0);
        const float4 z1 = *(const float4*)(xb + 2 * hw + rb + c1);
        const float4 z2 = *(const float4*)(xb + 2 * hw + rb + c2);

        const float xw[12] = {x0.x,x0.y,x0.z,x0.w, x1.x,x1.y,x1.z,x1.w, x2.x,x2.y,x2.z,x2.w};
        const float yw[12] = {y0.x,y0.y,y0.z,y0.w, y1.x,y1.y,y1.z,y1.w, y2.x,y2.y,y2.z,y2.w};
        const float zw[12] = {z0.x,z0.y,z0.z,z0.w, z1.x,z1.y,z1.z,z1.w, z2.x,z2.y,z2.z,z2.w};
        const int   mi[12] = {m0.x,m0.y,m0.z,m0.w, m1.x,m1.y,m1.z,m1.w, m2.x,m2.y,m2.z,m2.w};

        float mf[12];
#pragma unroll
        for (int j = 2; j <= 9; ++j) mf[j] = vf[j] * (float)mi[j];

        // Gaussian weights, once per (pixel, tap), shared across channels.
        float g[PX][5];
#pragma unroll
        for (int i = 0; i < PX; ++i) {
#pragma unroll
            for (int dx = 0; dx < 5; ++dx) {
                const int j = i + dx + 2;
                const float ax = xw[j] - cx[i];
                const float ay = yw[j] - cy[i];
                const float az = zw[j] - cz[i];
                const float d2 = ax * ax + ay * ay + az * az;
                g[i][dx] = mf[j] * __expf(-0.5f * d2);
            }
        }

        // Channel loop: 3 float4 loads + 20 FMA per channel.
#pragma unroll
        for (int c = 0; c < CPG; ++c) {
            const float* sp = smb + (size_t)c * hw + rb;
            const float4 s0 = *(const float4*)(sp + c0);
            const float4 s1 = *(const float4*)(sp + c1);
            const float4 s2 = *(const float4*)(sp + c2);
            const float sw[12] = {s0.x,s0.y,s0.z,s0.w, s1.x,s1.y,s1.z,s1.w, s2.x,s2.y,s2.z,s2.w};
#pragma unroll
            for (int i = 0; i < PX; ++i) {
                float a = acc[c][i];
#pragma unroll
                for (int dx = 0; dx < 5; ++dx)
                    a = fmaf(g[i][dx], sw[i + dx + 2], a);
                acc[c][i] = a;
            }
        }
    }

    float* ob = out + (size_t)n * CC * hw + (size_t)(cg * CPG) * hw + ctr;
#pragma unroll
    for (int c = 0; c < CPG; ++c)
        *(float4*)(ob + (size_t)c * hw) =
            make_float4(acc[c][0], acc[c][1], acc[c][2], acc[c][3]);
}

extern "C" void kernel_launch(void* const* d_in, const int* in_sizes, int n_in,
                              void* d_out, int out_size, void* d_ws, size_t ws_size,
                              hipStream_t stream) {
    const float* xyz     = (const float*)d_in[0];
    const float* softmax = (const float*)d_in[1];
    const int*   mask    = (const int*)d_in[2];
    float*       out     = (float*)d_out;

    dim3 block(256, 1, 1);
    dim3 grid(WW / (PX * 256), HH, NN * CG);   // 2 x 64 x 16 = 2048 blocks
    hipLaunchKernelGGL(lc_xyz_kernel, grid, block, 0, stream,
                       xyz, softmax, mask, out);
}